// Round 5
// baseline (270.681 us; speedup 1.0000x reference)
//
#include <hip/hip_runtime.h>
#include <hip/hip_bf16.h>

#define BB 2
#define NN 256
#define IN_DIM 256
#define EDGE_DIM 16
#define HH 8
#define DD 64
#define INNER 512
#define BH (BB*HH)
#define II 8   // i-rows per attn block

// Fused q/k/v projection. Nodes are read via wave-uniform addresses ->
// compiler emits s_load (SGPR), so the inner loop is 1 W vload + 8 FMA.
// z==0: q row-major  z==1: k transposed  z==2: v row-major
__global__ void proj_kernel(const float* __restrict__ nodes,
                            const float* __restrict__ Wq, const float* __restrict__ bq,
                            const float* __restrict__ Wk, const float* __restrict__ bk,
                            const float* __restrict__ Wv, const float* __restrict__ bv,
                            float* __restrict__ qf, float* __restrict__ kT,
                            float* __restrict__ vf) {
    const int z = blockIdx.z;
    const float* W; const float* bias; float* out; int mode;
    if (z == 0)      { W = Wq; bias = bq; out = qf; mode = 0; }
    else if (z == 1) { W = Wk; bias = bk; out = kT; mode = 1; }
    else             { W = Wv; bias = bv; out = vf; mode = 0; }

    const int tid = threadIdx.x;
    const int half = blockIdx.x;   // 0..1 (column half)
    const int rt = blockIdx.y;     // 0..63 (row tile of 8)
    const int r0 = rt * 8;
    const int col = half * 256 + tid;
    const float* __restrict__ nrow = nodes + r0 * IN_DIM;  // block-uniform base

    float acc[8];
#pragma unroll
    for (int rr = 0; rr < 8; ++rr) acc[rr] = 0.f;
#pragma unroll 8
    for (int k = 0; k < IN_DIM; ++k) {
        float wv = W[k * INNER + col];
#pragma unroll
        for (int rr = 0; rr < 8; ++rr) acc[rr] += nrow[rr * IN_DIM + k] * wv;
    }
    const float bv2 = bias[col];
    const int h = col >> 6, d = col & 63;
#pragma unroll
    for (int rr = 0; rr < 8; ++rr) {
        int r = r0 + rr;
        int b = r >> 8, n = r & 255;
        float val = acc[rr] + bv2;
        if (mode == 0)
            out[((b * HH + h) * NN + n) * DD + d] = val;
        else
            out[((b * HH + h) * DD + d) * NN + n] = val;
    }
}

// means[i] = mean_j sim[bh=0, i, j]   (the reference's [0]-sliced mean)
__global__ void means_kernel(const float* __restrict__ q,   // (BH,N,D)
                             const float* __restrict__ kT,  // (BH,D,N)
                             const float* __restrict__ edges,
                             const float* __restrict__ We,
                             const float* __restrict__ be,
                             float* __restrict__ means) {
    const int i = blockIdx.x;
    const int tid = threadIdx.x;
    __shared__ float qsh[DD];
    __shared__ float tsh[EDGE_DIM + 1];
    __shared__ float wred[4];
    if (tid < DD) qsh[tid] = q[i * DD + tid];    // bh = 0
    __syncthreads();
    if (tid < EDGE_DIM) {
        float s = 0.f;
        for (int d = 0; d < DD; ++d) s += qsh[d] * We[tid * INNER + d];  // h=0
        tsh[tid] = s;
    } else if (tid == EDGE_DIM) {
        float s = 0.f;
        for (int d = 0; d < DD; ++d) s += qsh[d] * be[d];
        tsh[EDGE_DIM] = s;
    }
    __syncthreads();
    const int j = tid;
    float sim = 0.f;
    for (int d = 0; d < DD; ++d) sim += qsh[d] * kT[d * NN + j];  // bh = 0
    float ed = 0.f;
    const float* erow = &edges[(i * NN + j) * EDGE_DIM];          // b = 0
#pragma unroll
    for (int c = 0; c < EDGE_DIM; ++c) ed += erow[c] * tsh[c];
    sim = (sim + ed + tsh[EDGE_DIM]) * 0.125f;
    float s = sim;
    for (int o = 32; o > 0; o >>= 1) s += __shfl_down(s, o, 64);
    if ((tid & 63) == 0) wred[tid >> 6] = s;
    __syncthreads();
    if (tid == 0) means[i] = (wred[0] + wred[1] + wred[2] + wred[3]) * (1.f / NN);
}

// One block per (bh, i-tile of II=8 rows), 512 threads.
// Group g = tid>>8 owns rows [g*4, g*4+4) in the score/softmax phase.
__global__ void attn_kernel(const float* __restrict__ q,
                            const float* __restrict__ kT,
                            const float* __restrict__ v,
                            const float* __restrict__ edges,
                            const float* __restrict__ adj,
                            const float* __restrict__ We,
                            const float* __restrict__ be,
                            const float* __restrict__ means,
                            float* __restrict__ out) {
    const int blk = blockIdx.x;           // BH * (NN/II) = 512
    const int bh = blk >> 5;
    const int it = blk & 31;
    const int i0 = it * II;
    const int b = bh >> 3, h = bh & 7;
    const int tid = threadIdx.x;          // 0..511
    const int j = tid & 255;
    const int g = tid >> 8;               // 0,1

    __shared__ float qsh[II][DD];                 // 2 KB
    __shared__ float tsh[II][EDGE_DIM + 1];
    __shared__ float attn_sh[II][NN];             // 8 KB
    __shared__ float red[8][II][DD];              // 16 KB
    __shared__ float wred2[32][II][EDGE_DIM];     // 16 KB
    __shared__ float wsh[II][EDGE_DIM];
    __shared__ float dred[II][4];
    __shared__ float msh[II];
    __shared__ float dsh[II];
    __shared__ float scoef_sh[II];

    {   // qsh: exactly 512 elements
        int ii = tid >> 6, d = tid & 63;
        qsh[ii][d] = q[(bh * NN + i0 + ii) * DD + d];
    }
    if (tid < II) msh[tid] = means[i0 + tid];
    __syncthreads();

    if (tid < II * (EDGE_DIM + 1)) {
        int ii = tid / (EDGE_DIM + 1), c = tid % (EDGE_DIM + 1);
        float s = 0.f;
        if (c < EDGE_DIM) {
            for (int d = 0; d < DD; ++d) s += qsh[ii][d] * We[c * INNER + h * DD + d];
        } else {
            for (int d = 0; d < DD; ++d) s += qsh[ii][d] * be[h * DD + d];
        }
        tsh[ii][c] = s;
    }
    __syncthreads();

    // --- scores: each group computes 4 rows ---
    const int iiB = g * 4;
    float sim[4] = {0.f, 0.f, 0.f, 0.f};
    const float* kbase = &kT[bh * DD * NN];
    for (int d = 0; d < DD; ++d) {
        float kv = kbase[d * NN + j];
#pragma unroll
        for (int r = 0; r < 4; ++r) sim[r] += qsh[iiB + r][d] * kv;
    }
    float x[4];
#pragma unroll
    for (int r = 0; r < 4; ++r) {
        const int ii = iiB + r;
        const float4* e4 = (const float4*)&edges[((b * NN + i0 + ii) * NN + j) * EDGE_DIM];
        float4 e0 = e4[0], e1 = e4[1], e2 = e4[2], e3 = e4[3];
        float ed = tsh[ii][EDGE_DIM];
        ed += e0.x * tsh[ii][0] + e0.y * tsh[ii][1] + e0.z * tsh[ii][2] + e0.w * tsh[ii][3];
        ed += e1.x * tsh[ii][4] + e1.y * tsh[ii][5] + e1.z * tsh[ii][6] + e1.w * tsh[ii][7];
        ed += e2.x * tsh[ii][8] + e2.y * tsh[ii][9] + e2.z * tsh[ii][10] + e2.w * tsh[ii][11];
        ed += e3.x * tsh[ii][12] + e3.y * tsh[ii][13] + e3.z * tsh[ii][14] + e3.w * tsh[ii][15];
        float s = (sim[r] + ed) * 0.125f;
        x[r] = __expf(s - msh[ii]) * adj[(b * NN + i0 + ii) * NN + j];
    }

    // --- denominators (denom==0 -> 1) ---
    const int w = tid >> 6;   // wave 0..7
#pragma unroll
    for (int r = 0; r < 4; ++r) {
        float s = x[r];
        for (int o = 32; o > 0; o >>= 1) s += __shfl_down(s, o, 64);
        if ((tid & 63) == 0) dred[iiB + r][w & 3] = s;
    }
    __syncthreads();
    if (tid < II) {
        float denom = dred[tid][0] + dred[tid][1] + dred[tid][2] + dred[tid][3];
        scoef_sh[tid] = (denom == 0.f) ? 0.f : 1.f;
        dsh[tid] = (denom == 0.f) ? 1.f : denom;
    }
    __syncthreads();
#pragma unroll
    for (int r = 0; r < 4; ++r) attn_sh[iiB + r][j] = x[r] / dsh[iiB + r];
    __syncthreads();

    // --- attn @ v: 8 partials of 32 j each ---
    {
        const int d = tid & 63, part = tid >> 6;
        float acc[II];
#pragma unroll
        for (int ii = 0; ii < II; ++ii) acc[ii] = 0.f;
        const float* vb = &v[(bh * NN + part * 32) * DD + d];
        for (int jj = 0; jj < 32; ++jj) {
            float av = vb[jj * DD];
#pragma unroll
            for (int ii = 0; ii < II; ++ii) acc[ii] += attn_sh[ii][part * 32 + jj] * av;
        }
#pragma unroll
        for (int ii = 0; ii < II; ++ii) red[part][ii][d] = acc[ii];
    }
    // --- w[ii][c] = sum_j attn[ii][j] * edges[b,i0+ii,j,c]: 32 partials of 8 j ---
    {
        const int c = tid & 15, p = tid >> 4;   // p = 0..31
        float accw[II];
#pragma unroll
        for (int ii = 0; ii < II; ++ii) accw[ii] = 0.f;
        for (int jj = 0; jj < 8; ++jj) {
            int jr = p * 8 + jj;
#pragma unroll
            for (int ii = 0; ii < II; ++ii)
                accw[ii] += attn_sh[ii][jr] *
                            edges[((b * NN + i0 + ii) * NN + jr) * EDGE_DIM + c];
        }
#pragma unroll
        for (int ii = 0; ii < II; ++ii) wred2[p][ii][c] = accw[ii];
    }
    __syncthreads();
    if (tid < II * EDGE_DIM) {
        int ii = tid >> 4, c = tid & 15;
        float t = 0.f;
#pragma unroll
        for (int p = 0; p < 32; ++p) t += wred2[p][ii][c];
        wsh[ii][c] = t;
    }
    __syncthreads();

    // --- epilogue: exactly 512 outputs ---
    {
        int ii = tid >> 6, d = tid & 63;
        float o = 0.f;
#pragma unroll
        for (int part = 0; part < 8; ++part) o += red[part][ii][d];
        float extra = scoef_sh[ii] * be[h * DD + d];
#pragma unroll
        for (int c = 0; c < EDGE_DIM; ++c)
            extra += wsh[ii][c] * We[c * INNER + h * DD + d];
        out[(b * NN + i0 + ii) * INNER + h * DD + d] = o + extra;
    }
}

extern "C" void kernel_launch(void* const* d_in, const int* in_sizes, int n_in,
                              void* d_out, int out_size, void* d_ws, size_t ws_size,
                              hipStream_t stream) {
    const float* nodes = (const float*)d_in[0];
    const float* edges = (const float*)d_in[1];
    const float* adj   = (const float*)d_in[2];
    const float* Wq = (const float*)d_in[3];
    const float* bq = (const float*)d_in[4];
    const float* Wk = (const float*)d_in[5];
    const float* bk = (const float*)d_in[6];
    const float* Wv = (const float*)d_in[7];
    const float* bv = (const float*)d_in[8];
    const float* We = (const float*)d_in[9];
    const float* be = (const float*)d_in[10];
    float* out = (float*)d_out;

    float* qf = (float*)d_ws;            // BH*N*D
    float* kT = qf + BH * NN * DD;       // BH*D*N
    float* vf = kT + BH * NN * DD;       // BH*N*D
    float* means = vf + BH * NN * DD;    // N

    hipLaunchKernelGGL(proj_kernel, dim3(2, 64, 3), dim3(256), 0, stream,
                       nodes, Wq, bq, Wk, bk, Wv, bv, qf, kT, vf);
    hipLaunchKernelGGL(means_kernel, dim3(NN), dim3(256), 0, stream,
                       qf, kT, edges, We, be, means);
    hipLaunchKernelGGL(attn_kernel, dim3(BH * (NN / II)), dim3(512), 0, stream,
                       qf, kT, vf, edges, adj, We, be, means, out);
}

// Round 6
// 125.041 us; speedup vs baseline: 2.1647x; 2.1647x over previous
//
#include <hip/hip_runtime.h>
#include <hip/hip_bf16.h>

#define BB 2
#define NN 256
#define IN_DIM 256
#define EDGE_DIM 16
#define HH 8
#define DD 64
#define INNER 512
#define BH (BB*HH)
#define II 8   // i-rows per attn block

// Fused q/k/v projection, LDS-staged, float4 everywhere.
// Block: 256 threads = one 256-col half; 4 rows; k in chunks of 4.
// z==0: q row-major  z==1: k transposed  z==2: v row-major
__global__ __launch_bounds__(256, 4)
void proj_kernel(const float* __restrict__ nodes,
                 const float* __restrict__ Wq, const float* __restrict__ bq,
                 const float* __restrict__ Wk, const float* __restrict__ bk,
                 const float* __restrict__ Wv, const float* __restrict__ bv,
                 float* __restrict__ qf, float* __restrict__ kT,
                 float* __restrict__ vf) {
    const int z = blockIdx.z;
    const float* W; const float* bias; float* out; int mode;
    if (z == 0)      { W = Wq; bias = bq; out = qf; mode = 0; }
    else if (z == 1) { W = Wk; bias = bk; out = kT; mode = 1; }
    else             { W = Wv; bias = bv; out = vf; mode = 0; }

    const int tid = threadIdx.x;
    const int half = blockIdx.x;     // 0..1
    const int r0 = blockIdx.y * 4;   // 4 rows per block

    __shared__ float4 nsh4[4][IN_DIM / 4];   // 4 KB
    {   // stage 4 rows (256 float4), 1 per thread, coalesced
        int rr = tid >> 6, c4 = tid & 63;
        nsh4[rr][c4] = ((const float4*)nodes)[(r0 + rr) * (IN_DIM / 4) + c4];
    }
    __syncthreads();

    const int col = half * 256 + tid;
    float acc[4] = {0.f, 0.f, 0.f, 0.f};
#pragma unroll 4
    for (int kc = 0; kc < IN_DIM / 4; ++kc) {
        float4 n0 = nsh4[0][kc], n1 = nsh4[1][kc], n2 = nsh4[2][kc], n3 = nsh4[3][kc];
        float w0 = W[(kc * 4 + 0) * INNER + col];
        float w1 = W[(kc * 4 + 1) * INNER + col];
        float w2 = W[(kc * 4 + 2) * INNER + col];
        float w3 = W[(kc * 4 + 3) * INNER + col];
        acc[0] += n0.x * w0 + n0.y * w1 + n0.z * w2 + n0.w * w3;
        acc[1] += n1.x * w0 + n1.y * w1 + n1.z * w2 + n1.w * w3;
        acc[2] += n2.x * w0 + n2.y * w1 + n2.z * w2 + n2.w * w3;
        acc[3] += n3.x * w0 + n3.y * w1 + n3.z * w2 + n3.w * w3;
    }
    const float bv2 = bias[col];
    const int h = col >> 6, d = col & 63;
#pragma unroll
    for (int rr = 0; rr < 4; ++rr) {
        int r = r0 + rr;
        int b = r >> 8, n = r & 255;
        float val = acc[rr] + bv2;
        if (mode == 0)
            out[((b * HH + h) * NN + n) * DD + d] = val;
        else
            out[((b * HH + h) * DD + d) * NN + n] = val;
    }
}

// means[i] = mean_j sim[bh=0, i, j]   (the reference's [0]-sliced mean)
__global__ void means_kernel(const float* __restrict__ q,   // (BH,N,D)
                             const float* __restrict__ kT,  // (BH,D,N)
                             const float* __restrict__ edges,
                             const float* __restrict__ We,
                             const float* __restrict__ be,
                             float* __restrict__ means) {
    const int i = blockIdx.x;
    const int tid = threadIdx.x;
    __shared__ float qsh[DD];
    __shared__ float tsh[EDGE_DIM + 1];
    __shared__ float wred[4];
    if (tid < DD) qsh[tid] = q[i * DD + tid];    // bh = 0
    __syncthreads();
    if (tid < EDGE_DIM) {
        float s = 0.f;
        for (int d = 0; d < DD; ++d) s += qsh[d] * We[tid * INNER + d];  // h=0
        tsh[tid] = s;
    } else if (tid == EDGE_DIM) {
        float s = 0.f;
        for (int d = 0; d < DD; ++d) s += qsh[d] * be[d];
        tsh[EDGE_DIM] = s;
    }
    __syncthreads();
    const int j = tid;
    float sim = 0.f;
    for (int d = 0; d < DD; ++d) sim += qsh[d] * kT[d * NN + j];  // bh = 0
    float ed = 0.f;
    const float* erow = &edges[(i * NN + j) * EDGE_DIM];          // b = 0
#pragma unroll
    for (int c = 0; c < EDGE_DIM; ++c) ed += erow[c] * tsh[c];
    sim = (sim + ed + tsh[EDGE_DIM]) * 0.125f;
    float s = sim;
    for (int o = 32; o > 0; o >>= 1) s += __shfl_down(s, o, 64);
    if ((tid & 63) == 0) wred[tid >> 6] = s;
    __syncthreads();
    if (tid == 0) means[i] = (wred[0] + wred[1] + wred[2] + wred[3]) * (1.f / NN);
}

// One block per (bh, i-tile of II=8 rows), 256 threads.
// Softmax normalization is deferred to the epilogue (linear in attn row),
// and per-row numerators go straight to LDS -> tiny register footprint.
__global__ __launch_bounds__(256, 4)
void attn_kernel(const float* __restrict__ q,
                 const float* __restrict__ kT,
                 const float* __restrict__ v,
                 const float* __restrict__ edges,
                 const float* __restrict__ adj,
                 const float* __restrict__ We,
                 const float* __restrict__ be,
                 const float* __restrict__ means,
                 float* __restrict__ out) {
    const int blk = blockIdx.x;           // 512
    const int bh = blk >> 5;
    const int it = blk & 31;
    const int i0 = it * II;
    const int b = bh >> 3, h = bh & 7;
    const int tid = threadIdx.x;          // 0..255
    const int j = tid;

    __shared__ float qsh[II][DD];                 // 2 KB
    __shared__ float tsh[II][EDGE_DIM + 1];       // 544 B
    __shared__ float xsh[II][NN];                 // 8 KB  (numerators)
    __shared__ float red[4][II][DD];              // 8 KB
    __shared__ float wred2[16][II][EDGE_DIM];     // 8 KB
    __shared__ float wsh[II][EDGE_DIM];
    __shared__ float dred[II][4];
    __shared__ float msh[II];
    __shared__ float dinv[II];
    __shared__ float scoef_sh[II];

    for (int idx = tid; idx < II * DD; idx += 256) {
        int ii = idx >> 6, d = idx & 63;
        qsh[ii][d] = q[(bh * NN + i0 + ii) * DD + d];
    }
    if (tid < II) msh[tid] = means[i0 + tid];
    __syncthreads();

    if (tid < II * (EDGE_DIM + 1)) {
        int ii = tid / (EDGE_DIM + 1), c = tid % (EDGE_DIM + 1);
        float s = 0.f;
        if (c < EDGE_DIM) {
            for (int d = 0; d < DD; ++d) s += qsh[ii][d] * We[c * INNER + h * DD + d];
        } else {
            for (int d = 0; d < DD; ++d) s += qsh[ii][d] * be[h * DD + d];
        }
        tsh[ii][c] = s;
    }
    __syncthreads();

    // --- scores: sim[8] accumulated over d (kT read once, reused 8x) ---
    float sim[II];
#pragma unroll
    for (int ii = 0; ii < II; ++ii) sim[ii] = 0.f;
    const float* kbase = &kT[bh * DD * NN];
    for (int d = 0; d < DD; ++d) {
        float kv = kbase[d * NN + j];
#pragma unroll
        for (int ii = 0; ii < II; ++ii) sim[ii] += qsh[ii][d] * kv;
    }

    // --- per row: edge term, exp, mask; numerator -> LDS; reduce transient ---
    const int w = tid >> 6;   // wave 0..3
#pragma unroll
    for (int ii = 0; ii < II; ++ii) {
        const float4* e4 = (const float4*)&edges[((b * NN + i0 + ii) * NN + j) * EDGE_DIM];
        float4 e0 = e4[0], e1 = e4[1], e2 = e4[2], e3 = e4[3];
        float ed = tsh[ii][EDGE_DIM];
        ed += e0.x * tsh[ii][0] + e0.y * tsh[ii][1] + e0.z * tsh[ii][2] + e0.w * tsh[ii][3];
        ed += e1.x * tsh[ii][4] + e1.y * tsh[ii][5] + e1.z * tsh[ii][6] + e1.w * tsh[ii][7];
        ed += e2.x * tsh[ii][8] + e2.y * tsh[ii][9] + e2.z * tsh[ii][10] + e2.w * tsh[ii][11];
        ed += e3.x * tsh[ii][12] + e3.y * tsh[ii][13] + e3.z * tsh[ii][14] + e3.w * tsh[ii][15];
        float s = (sim[ii] + ed) * 0.125f;
        float x = __expf(s - msh[ii]) * adj[(b * NN + i0 + ii) * NN + j];
        xsh[ii][j] = x;
        for (int o = 32; o > 0; o >>= 1) x += __shfl_down(x, o, 64);
        if ((tid & 63) == 0) dred[ii][w] = x;
    }
    __syncthreads();
    if (tid < II) {
        float denom = dred[tid][0] + dred[tid][1] + dred[tid][2] + dred[tid][3];
        scoef_sh[tid] = (denom == 0.f) ? 0.f : 1.f;
        dinv[tid] = (denom == 0.f) ? 1.f : 1.f / denom;
    }
    __syncthreads();

    // --- x @ v (numerators): 4 partials of 64 j, float4 over j ---
    {
        const int d = tid & 63, part = tid >> 6;
        float acc[II];
#pragma unroll
        for (int ii = 0; ii < II; ++ii) acc[ii] = 0.f;
        const float* vb = &v[(bh * NN + part * 64) * DD + d];
        for (int jj4 = 0; jj4 < 16; ++jj4) {
            float av0 = vb[(jj4 * 4 + 0) * DD];
            float av1 = vb[(jj4 * 4 + 1) * DD];
            float av2 = vb[(jj4 * 4 + 2) * DD];
            float av3 = vb[(jj4 * 4 + 3) * DD];
#pragma unroll
            for (int ii = 0; ii < II; ++ii) {
                float4 x4 = *(const float4*)&xsh[ii][part * 64 + jj4 * 4];
                acc[ii] += x4.x * av0 + x4.y * av1 + x4.z * av2 + x4.w * av3;
            }
        }
#pragma unroll
        for (int ii = 0; ii < II; ++ii) red[part][ii][d] = acc[ii];
    }
    // --- w~[ii][c] = sum_j x[ii][j] * edges[b,i0+ii,j,c]: 16 partials of 16 j ---
    {
        const int c = tid & 15, p = tid >> 4;
        float accw[II];
#pragma unroll
        for (int ii = 0; ii < II; ++ii) accw[ii] = 0.f;
        for (int jj = 0; jj < 16; ++jj) {
            int jr = p * 16 + jj;
#pragma unroll
            for (int ii = 0; ii < II; ++ii)
                accw[ii] += xsh[ii][jr] *
                            edges[((b * NN + i0 + ii) * NN + jr) * EDGE_DIM + c];
        }
#pragma unroll
        for (int ii = 0; ii < II; ++ii) wred2[p][ii][c] = accw[ii];
    }
    __syncthreads();
    if (tid < II * EDGE_DIM) {
        int ii = tid >> 4, c = tid & 15;
        float t = 0.f;
#pragma unroll
        for (int p = 0; p < 16; ++p) t += wred2[p][ii][c];
        wsh[ii][c] = t;
    }
    __syncthreads();

    // --- epilogue: normalize once ---
    for (int idx = tid; idx < II * DD; idx += 256) {
        int ii = idx >> 6, d = idx & 63;
        float o = red[0][ii][d] + red[1][ii][d] + red[2][ii][d] + red[3][ii][d];
#pragma unroll
        for (int c = 0; c < EDGE_DIM; ++c)
            o += wsh[ii][c] * We[c * INNER + h * DD + d];
        out[(b * NN + i0 + ii) * INNER + h * DD + d] =
            o * dinv[ii] + scoef_sh[ii] * be[h * DD + d];
    }
}

extern "C" void kernel_launch(void* const* d_in, const int* in_sizes, int n_in,
                              void* d_out, int out_size, void* d_ws, size_t ws_size,
                              hipStream_t stream) {
    const float* nodes = (const float*)d_in[0];
    const float* edges = (const float*)d_in[1];
    const float* adj   = (const float*)d_in[2];
    const float* Wq = (const float*)d_in[3];
    const float* bq = (const float*)d_in[4];
    const float* Wk = (const float*)d_in[5];
    const float* bk = (const float*)d_in[6];
    const float* Wv = (const float*)d_in[7];
    const float* bv = (const float*)d_in[8];
    const float* We = (const float*)d_in[9];
    const float* be = (const float*)d_in[10];
    float* out = (float*)d_out;

    float* qf = (float*)d_ws;            // BH*N*D
    float* kT = qf + BH * NN * DD;       // BH*D*N
    float* vf = kT + BH * NN * DD;       // BH*N*D
    float* means = vf + BH * NN * DD;    // N

    hipLaunchKernelGGL(proj_kernel, dim3(2, 128, 3), dim3(256), 0, stream,
                       nodes, Wq, bq, Wk, bk, Wv, bv, qf, kT, vf);
    hipLaunchKernelGGL(means_kernel, dim3(NN), dim3(256), 0, stream,
                       qf, kT, edges, We, be, means);
    hipLaunchKernelGGL(attn_kernel, dim3(BH * (NN / II)), dim3(256), 0, stream,
                       qf, kT, vf, edges, adj, We, be, means, out);
}